// Round 19
// baseline (74043.164 us; speedup 1.0000x reference)
//
#include <hip/hip_runtime.h>

// Farthest point sampling, B=32, N=32768, npoint=4096.
// R19 = R18 base (static 128KB LDS z, pair ds_read_b64, 3-slot 32-bit
// two-phase reduce, amdgpu_num_vgpr(128)) with two cuts:
//  (1) inner loop tracks VALUE only: best = fmaxf(best, nd) (1 op vs
//      cmp+2 cndmask). Index recovered in rare phase-B scan: candidates
//      (best==M, ~1/block) rescan their 32 dist regs for first ==M ->
//      atomicMin global index. First-occurrence preserved (local order
//      ascends with global index; min across candidates = numpy argmax).
//  (2) centroid via LDS, not global: after B2 the WINNER thread (its bi ==
//      s_idx[p]) writes its own coords (px/py regs + pz LDS) to s_c and
//      writes out_idx/out_xyz directly; B3 publishes. Removes the serial
//      per-step L2 round-trip (w known only at B2) + tid0 output stores.
//      Seed (idx 1): tid0 owns g=1 (c=0,j=1) -> writes s_c + out[0] at init.
// PASSING arithmetic (R6, bit-exact): d = fmaf(dz,dz, fmaf(dx,dx, dy*dy)),
// contract(off), fminf chain; f32 dist>=0 so u32 bit compare == float
// compare for the 32-bit LDS atomics.
// Output float32: [B*NPOINT] idx, [B*NPOINT*3] coords.

#define BATCH  32
#define NPTS   32768
#define NPOINT 4096
#define NT     1024
#define NCH    16            // chunks of 2: 32 points per thread

__global__ __launch_bounds__(NT, 1)
__attribute__((amdgpu_num_vgpr(128)))
void fps_kernel(
    const float* __restrict__ xyz,   // [B, N, 3] float32
    float* __restrict__ out_idx,     // [B, NPOINT]
    float* __restrict__ out_xyz)     // [B, NPOINT, 3]
{
#pragma clang fp contract(off)
    __shared__ float pz_lds[NPTS];               // 128 KB static
    __shared__ unsigned int s_val[3];            // dist bits (>=0, monotone)
    __shared__ int s_idx[3];                     // winning global index
    __shared__ float s_c[3];                     // current centroid

    const int b   = blockIdx.x;
    const int tid = threadIdx.x;
    const float* base = xyz + (size_t)b * NPTS * 3;

    float px[NCH * 2], py[NCH * 2], dist[NCH * 2];
#pragma unroll
    for (int c = 0; c < NCH; ++c) {
#pragma unroll
        for (int j = 0; j < 2; ++j) {
            const int i = c * 2 + j;
            const int g = c * 2048 + 2 * tid + j;
            px[i] = base[g * 3 + 0];
            py[i] = base[g * 3 + 1];
            pz_lds[g] = base[g * 3 + 2];
            dist[i] = 1e10f;
        }
    }
    if (tid == 0) {
        s_val[0] = 0u; s_val[1] = 0u; s_val[2] = 0u;
        s_idx[0] = 0x7fffffff; s_idx[1] = 0x7fffffff; s_idx[2] = 0x7fffffff;
        // Seed centroid = point index 1 (RAN=False): tid0's c=0,j=1 slot.
        s_c[0] = px[1]; s_c[1] = py[1]; s_c[2] = base[1 * 3 + 2];
        out_idx[(size_t)b * NPOINT + 0] = 1.0f;
        float* o = out_xyz + (size_t)b * NPOINT * 3;
        o[0] = px[1]; o[1] = py[1]; o[2] = base[1 * 3 + 2];
    }
    __syncthreads();                       // pz_lds + slots + seed ready

    int p = 0;   // rotating slot index k%3

    // Each iteration consumes centroid c_k (in s_c) and selects/writes k+1.
    for (int k = 0; k < NPOINT - 1; ++k) {
        const float cx = s_c[0], cy = s_c[1], cz = s_c[2];

        // Distance update; track VALUE only.
        float best = -1.0f;
#pragma unroll
        for (int c = 0; c < NCH; ++c) {
            const float2 zz = *(const float2*)&pz_lds[c * 2048 + 2 * tid];
            const float pzv[2] = { zz.x, zz.y };
#pragma unroll
            for (int j = 0; j < 2; ++j) {
                const int i = c * 2 + j;
                const float dx = px[i] - cx;
                const float dy = py[i] - cy;
                const float dz = pzv[j] - cz;
                const float d  = fmaf(dz, dz, fmaf(dx, dx, dy * dy));
                const float nd = fminf(dist[i], d);
                dist[i] = nd;
                best = fmaxf(best, nd);
            }
        }

        // Phase A: value-only wave butterfly max.
        float m = best;
#pragma unroll
        for (int off = 1; off < 64; off <<= 1)
            m = fmaxf(m, __shfl_xor(m, off, 64));
        if ((tid & 63) == 0)
            atomicMax(&s_val[p], __float_as_uint(m));
        __syncthreads();                   // B1: block max known
        const float M = __uint_as_float(s_val[p]);

        // Phase B (rare path): candidates find their FIRST dist==M.
        int mybi = 0x7fffffff;
        if (best == M) {
            int li = 0;
#pragma unroll
            for (int i = 31; i >= 0; --i)
                if (dist[i] == M) li = i;          // ends at smallest i
            mybi = (li >> 1) * 2048 + 2 * tid + (li & 1);
            atomicMin(&s_idx[p], mybi);
        }
        __syncthreads();                   // B2: winning index known
        const int widx = s_idx[p];
        // Winner thread publishes next centroid + outputs (no global read).
        if (best == M && mybi == widx) {
            const int li = ((widx - 2 * tid) >> 11) * 2 + (widx & 1);
            const float wx = px[li], wy = py[li];
            const float wz = pz_lds[widx];
            s_c[0] = wx; s_c[1] = wy; s_c[2] = wz;
            out_idx[(size_t)b * NPOINT + (k + 1)] = (float)widx;
            float* o = out_xyz + ((size_t)b * NPOINT + (k + 1)) * 3;
            o[0] = wx; o[1] = wy; o[2] = wz;
        }
        // Reset slot for step k+2 (barriers of step k+1 order this write
        // before that slot's next atomics; its readers finished at k-1).
        const int pn2 = (p >= 1) ? (p - 1) : 2;   // (k+2)%3
        if (tid == 0) { s_val[pn2] = 0u; s_idx[pn2] = 0x7fffffff; }
        __syncthreads();                   // B3: s_c published
        p = (p == 2) ? 0 : (p + 1);
    }
}

extern "C" void kernel_launch(void* const* d_in, const int* in_sizes, int n_in,
                              void* d_out, int out_size, void* d_ws, size_t ws_size,
                              hipStream_t stream) {
    const float* xyz = (const float*)d_in[0];
    float* out = (float*)d_out;
    float* out_idx = out;                              // B*NPOINT floats
    float* out_xyz = out + (size_t)BATCH * NPOINT;     // B*NPOINT*3 floats

    fps_kernel<<<BATCH, NT, 0, stream>>>(xyz, out_idx, out_xyz);
}

// Round 20
// 9266.084 us; speedup vs baseline: 7.9908x; 7.9908x over previous
//
#include <hip/hip_runtime.h>

// Farthest point sampling, B=32, N=32768, npoint=4096.
// R20 = R19 with the rule-#20 violation fixed: R19's winner-publish read
// px[li] with RUNTIME li -> compiler demoted px/py to scratch -> 6 GB/launch
// HBM fetch, 74ms. Now the phase-B rescan extracts the winner's coords with
// CONSTANT indices (cndmask chain, register-resident):
//   for i=31..0: if (dist[i]==M) { li=i; wx=px[i]; wy=py[i]; }
// Winner thread publishes wx/wy/pz_lds[widx] to s_c + writes outputs.
// Structure (validated R18/R19): static 128KB LDS z, pair ds_read_b64,
// value-only inner loop (best=fmaxf), value butterfly, 3-slot 32-bit
// two-phase reduce (ds_max_u32 / ds_min_u32), centroid from LDS (no
// per-step global read), 3 barriers/step, amdgpu_num_vgpr(128).
// PASSING arithmetic (R6, bit-exact): d = fmaf(dz,dz, fmaf(dx,dx, dy*dy)),
// contract(off), fminf chain; first-occurrence argmax preserved (local
// scan order ascends with global index; min across candidates).
// Output float32: [B*NPOINT] idx, [B*NPOINT*3] coords.

#define BATCH  32
#define NPTS   32768
#define NPOINT 4096
#define NT     1024
#define NCH    16            // chunks of 2: 32 points per thread

__global__ __launch_bounds__(NT, 1)
__attribute__((amdgpu_num_vgpr(128)))
void fps_kernel(
    const float* __restrict__ xyz,   // [B, N, 3] float32
    float* __restrict__ out_idx,     // [B, NPOINT]
    float* __restrict__ out_xyz)     // [B, NPOINT, 3]
{
#pragma clang fp contract(off)
    __shared__ float pz_lds[NPTS];               // 128 KB static
    __shared__ unsigned int s_val[3];            // dist bits (>=0, monotone)
    __shared__ int s_idx[3];                     // winning global index
    __shared__ float s_c[3];                     // current centroid

    const int b   = blockIdx.x;
    const int tid = threadIdx.x;
    const float* base = xyz + (size_t)b * NPTS * 3;

    float px[NCH * 2], py[NCH * 2], dist[NCH * 2];
#pragma unroll
    for (int c = 0; c < NCH; ++c) {
#pragma unroll
        for (int j = 0; j < 2; ++j) {
            const int i = c * 2 + j;
            const int g = c * 2048 + 2 * tid + j;
            px[i] = base[g * 3 + 0];
            py[i] = base[g * 3 + 1];
            pz_lds[g] = base[g * 3 + 2];
            dist[i] = 1e10f;
        }
    }
    if (tid == 0) {
        s_val[0] = 0u; s_val[1] = 0u; s_val[2] = 0u;
        s_idx[0] = 0x7fffffff; s_idx[1] = 0x7fffffff; s_idx[2] = 0x7fffffff;
        // Seed centroid = point index 1 (RAN=False): tid0's c=0,j=1 slot.
        s_c[0] = px[1]; s_c[1] = py[1]; s_c[2] = base[1 * 3 + 2];
        out_idx[(size_t)b * NPOINT + 0] = 1.0f;
        float* o = out_xyz + (size_t)b * NPOINT * 3;
        o[0] = px[1]; o[1] = py[1]; o[2] = base[1 * 3 + 2];
    }
    __syncthreads();                       // pz_lds + slots + seed ready

    int p = 0;   // rotating slot index k%3

    // Each iteration consumes centroid c_k (in s_c) and selects/writes k+1.
    for (int k = 0; k < NPOINT - 1; ++k) {
        const float cx = s_c[0], cy = s_c[1], cz = s_c[2];

        // Distance update; track VALUE only.
        float best = -1.0f;
#pragma unroll
        for (int c = 0; c < NCH; ++c) {
            const float2 zz = *(const float2*)&pz_lds[c * 2048 + 2 * tid];
            const float pzv[2] = { zz.x, zz.y };
#pragma unroll
            for (int j = 0; j < 2; ++j) {
                const int i = c * 2 + j;
                const float dx = px[i] - cx;
                const float dy = py[i] - cy;
                const float dz = pzv[j] - cz;
                const float d  = fmaf(dz, dz, fmaf(dx, dx, dy * dy));
                const float nd = fminf(dist[i], d);
                dist[i] = nd;
                best = fmaxf(best, nd);
            }
        }

        // Phase A: value-only wave butterfly max.
        float m = best;
#pragma unroll
        for (int off = 1; off < 64; off <<= 1)
            m = fmaxf(m, __shfl_xor(m, off, 64));
        if ((tid & 63) == 0)
            atomicMax(&s_val[p], __float_as_uint(m));
        __syncthreads();                   // B1: block max known
        const float M = __uint_as_float(s_val[p]);

        // Phase B (rare, exec-masked): candidates find their FIRST dist==M
        // and extract coords with CONSTANT indices (no scratch demotion).
        int mybi = 0x7fffffff;
        float wx = 0.0f, wy = 0.0f;
        if (best == M) {
            int li = 0;
#pragma unroll
            for (int i = 31; i >= 0; --i)
                if (dist[i] == M) { li = i; wx = px[i]; wy = py[i]; }
            mybi = (li >> 1) * 2048 + 2 * tid + (li & 1);
            atomicMin(&s_idx[p], mybi);
        }
        __syncthreads();                   // B2: winning index known
        const int widx = s_idx[p];
        // Winner thread publishes next centroid + outputs (regs + LDS only).
        if (mybi == widx) {
            const float wz = pz_lds[widx];
            s_c[0] = wx; s_c[1] = wy; s_c[2] = wz;
            out_idx[(size_t)b * NPOINT + (k + 1)] = (float)widx;
            float* o = out_xyz + ((size_t)b * NPOINT + (k + 1)) * 3;
            o[0] = wx; o[1] = wy; o[2] = wz;
        }
        // Reset slot for step k+2 (barriers of step k+1 order this write
        // before that slot's next atomics; its readers finished at k-1).
        const int pn2 = (p >= 1) ? (p - 1) : 2;   // (k+2)%3
        if (tid == 0) { s_val[pn2] = 0u; s_idx[pn2] = 0x7fffffff; }
        __syncthreads();                   // B3: s_c published
        p = (p == 2) ? 0 : (p + 1);
    }
}

extern "C" void kernel_launch(void* const* d_in, const int* in_sizes, int n_in,
                              void* d_out, int out_size, void* d_ws, size_t ws_size,
                              hipStream_t stream) {
    const float* xyz = (const float*)d_in[0];
    float* out = (float*)d_out;
    float* out_idx = out;                              // B*NPOINT floats
    float* out_xyz = out + (size_t)BATCH * NPOINT;     // B*NPOINT*3 floats

    fps_kernel<<<BATCH, NT, 0, stream>>>(xyz, out_idx, out_xyz);
}